// Round 8
// baseline (708.051 us; speedup 1.0000x reference)
//
#include <hip/hip_runtime.h>
#include <hip/hip_fp16.h>

// GCN 2-layer. N=250000, E=4000000, 18 -> 16 -> 1.
// R8: propagation blocking. R4/R5/R7 proved the random hs1 gather is pinned
// at 4M requests / 350us (= 0.6 req/cyc/XCD) regardless of bytes (64B vs
// 32B rows), occupancy (37->61%), or window ordering: a fabric concurrency
// wall (tags/latency), not a byte wall. So eliminate the random READ:
//  - bin edges by src bucket as well (srecs = (dst_slot<<8)|src_local)
//  - h1msg: per src-bucket, compute 256 fp16 rows in LDS (fuses h1), then
//    stream records and WRITE each 32B message to its dst-ordered slot.
//    Random stores are posted (no latency chain) unlike loads.
//  - agg1: message stream is now a SEQUENTIAL read (128MB) + LDS accumulate.
// Msg buffer chunked over dst-buckets to fit ws_size (buffer reused).
//
// out[d] = dis[d] * (sum_{s->d} hs[s] + hs[d]) + bias, hs pre-scaled by dis.

#define NB_BITS 8
#define BN (1 << NB_BITS)       // 256 nodes per bucket (both src and dst)
#define NBINS 1024              // >= 977 buckets
#define BIN_TPB 512
#define BIN_CHUNK 8192
#define AGG_TPB 512
#define ASTRIDE 17              // LDS pad: kills bank aliasing on acc
#define UF 8

// per-block LDS histograms of dst buckets AND src buckets
__global__ void bhist_kernel(const int* __restrict__ src, const int* __restrict__ dst,
                             int* __restrict__ bcnt_d, int* __restrict__ bcnt_s, int E) {
    __shared__ int cd[NBINS];
    __shared__ int cs[NBINS];
    int t = threadIdx.x;
    for (int i = t; i < NBINS; i += BIN_TPB) { cd[i] = 0; cs[i] = 0; }
    __syncthreads();
    int base = blockIdx.x * BIN_CHUNK;
    int end = min(base + BIN_CHUNK, E);
#pragma unroll 4
    for (int e = base + t; e < end; e += BIN_TPB) {
        atomicAdd(&cd[dst[e] >> NB_BITS], 1);
        atomicAdd(&cs[src[e] >> NB_BITS], 1);
    }
    __syncthreads();
    for (int i = t; i < NBINS; i += BIN_TPB) {
        if (cd[i] > 0) atomicAdd(&bcnt_d[i], cd[i]);
        if (cs[i] > 0) atomicAdd(&bcnt_s[i], cs[i]);
    }
}

// exclusive scan of bcnt[NBINS] -> bstart, cursor (launched twice: dst, src)
__global__ void bscan_kernel(const int* __restrict__ bcnt, int* __restrict__ bstart,
                             int* __restrict__ cursor) {
    __shared__ int s[NBINS];
    int t = threadIdx.x;  // NBINS threads
    int v = bcnt[t];
    s[t] = v;
    __syncthreads();
    for (int off = 1; off < NBINS; off <<= 1) {
        int add = (t >= off) ? s[t - off] : 0;
        __syncthreads();
        s[t] += add;
        __syncthreads();
    }
    int excl = s[t] - v;
    bstart[t] = excl;
    cursor[t] = excl;
    if (t == NBINS - 1) bstart[NBINS] = s[t];
}

// place edges both ways:
//   pairs[p] = (src<<8 | dst&255)      in dst-bucket order (slot p)
//   srecs[q] = (p<<8  | src&255)       in src-bucket order
__global__ void bplace_kernel(const int* __restrict__ src, const int* __restrict__ dst,
                              int* __restrict__ dcursor, int* __restrict__ scursor,
                              int* __restrict__ pairs, int* __restrict__ srecs, int E) {
    __shared__ int cd[NBINS];
    __shared__ int cs[NBINS];
    int t = threadIdx.x;
    for (int i = t; i < NBINS; i += BIN_TPB) { cd[i] = 0; cs[i] = 0; }
    __syncthreads();
    int base = blockIdx.x * BIN_CHUNK;
    int end = min(base + BIN_CHUNK, E);
#pragma unroll 4
    for (int e = base + t; e < end; e += BIN_TPB) {
        atomicAdd(&cd[dst[e] >> NB_BITS], 1);
        atomicAdd(&cs[src[e] >> NB_BITS], 1);
    }
    __syncthreads();
    for (int i = t; i < NBINS; i += BIN_TPB) {
        int c = cd[i];
        cd[i] = (c > 0) ? atomicAdd(&dcursor[i], c) : 0;
        int c2 = cs[i];
        cs[i] = (c2 > 0) ? atomicAdd(&scursor[i], c2) : 0;
    }
    __syncthreads();
#pragma unroll 2
    for (int e = base + t; e < end; e += BIN_TPB) {
        int d = dst[e];
        int sv = src[e];
        int p = atomicAdd(&cd[d >> NB_BITS], 1);
        pairs[p] = (sv << NB_BITS) | (d & (BN - 1));   // sv<2^18, <<8 fits
        int q = atomicAdd(&cs[sv >> NB_BITS], 1);
        srecs[q] = (p << NB_BITS) | (sv & (BN - 1));   // p<2^22, <<8 fits
    }
}

// per-bucket in-degree via LDS counters -> dis = rsqrt(deg+1)
__global__ void degdis_kernel(const int* __restrict__ pairs, const int* __restrict__ bstart,
                              float* __restrict__ dis, int N) {
    __shared__ int cnt[BN];
    int b = blockIdx.x, t = threadIdx.x;
    for (int i = t; i < BN; i += blockDim.x) cnt[i] = 0;
    __syncthreads();
    int s0 = bstart[b], s1 = bstart[b + 1];
#pragma unroll 4
    for (int e = s0 + t; e < s1; e += blockDim.x)
        atomicAdd(&cnt[pairs[e] & (BN - 1)], 1);
    __syncthreads();
    int nbase = b << NB_BITS;
    for (int i = t; i < BN; i += blockDim.x) {
        int n = nbase + i;
        if (n < N) dis[n] = rsqrtf((float)cnt[i] + 1.0f);
    }
}

// fused h1 + message scatter. Block = one src bucket.
// Phase A: threads 0..255 compute row n = fp16(x[n]@W1 * dis[n]) into LDS
//          (and once, writeH, into global hs1h for the self-terms).
// Phase B: stream this bucket's srecs; 16 lanes/record write the 32B message
//          to its dst-ordered slot (posted random stores, no latency chain).
__global__ void h1msg_kernel(const float* __restrict__ x, const float* __restrict__ W1,
                             const float* __restrict__ dis, const int* __restrict__ srecs,
                             const int* __restrict__ sstart, const int* __restrict__ bstart,
                             __half* __restrict__ hs1h, ushort* __restrict__ msgu,
                             int b0, int b1, int writeH, int N) {
    __shared__ float w[18 * 16];
    __shared__ ushort rows[BN * 17];
    int t = threadIdx.x, sb = blockIdx.x;
    for (int i = t; i < 18 * 16; i += blockDim.x) w[i] = W1[i];
    __syncthreads();
    if (t < BN) {
        int n = (sb << NB_BITS) + t;
        if (n < N) {
            const float2* x2 = (const float2*)(x + (size_t)n * 18);
            float xv[18];
#pragma unroll
            for (int k = 0; k < 9; k++) {
                float2 v = x2[k];
                xv[2 * k] = v.x;
                xv[2 * k + 1] = v.y;
            }
            float d = dis[n];
            float acc[16];
#pragma unroll
            for (int f = 0; f < 16; f++) acc[f] = 0.0f;
#pragma unroll
            for (int k = 0; k < 18; k++) {
                float xk = xv[k];
#pragma unroll
                for (int f = 0; f < 16; f++) acc[f] = fmaf(xk, w[k * 16 + f], acc[f]);
            }
            ushort us[16];
#pragma unroll
            for (int f = 0; f < 16; f++)
                us[f] = __half_as_ushort(__float2half_rn(acc[f] * d));
#pragma unroll
            for (int f = 0; f < 16; f++) rows[t * 17 + f] = us[f];
            if (writeH) {
                unsigned int u[8];
#pragma unroll
                for (int q = 0; q < 8; q++)
                    u[q] = (unsigned int)us[2 * q] | ((unsigned int)us[2 * q + 1] << 16);
                uint4* outp = (uint4*)(hs1h + (size_t)n * 16);
                outp[0] = make_uint4(u[0], u[1], u[2], u[3]);
                outp[1] = make_uint4(u[4], u[5], u[6], u[7]);
            }
        }
    }
    __syncthreads();
    int S0 = bstart[b0], S1 = bstart[b1];
    int q0 = sstart[sb], q1 = sstart[sb + 1];
    int f = t & 15;
    const int G = AGG_TPB / 16;  // 32 record-groups
#pragma unroll 4
    for (int q = q0 + (t >> 4); q < q1; q += G) {
        int rec = srecs[q];
        int p = rec >> NB_BITS;       // rec < 2^30, arithmetic shift fine
        int sl = rec & (BN - 1);
        if (p >= S0 && p < S1)
            msgu[(size_t)(p - S0) * 16 + f] = rows[sl * 17 + f];
    }
}

// layer-1: SEQUENTIAL message stream + per-bucket LDS accumulate.
// epilogue: relu + W2 dot + dis scale -> hs2 (unchanged from R7)
__global__ void agg1_kernel(const int* __restrict__ pairs, const int* __restrict__ bstart,
                            const ushort* __restrict__ msgu, const __half* __restrict__ hs1h,
                            const float* __restrict__ dis, const float* __restrict__ b1,
                            const float* __restrict__ W2, float* __restrict__ hs2,
                            int b0, int N) {
    __shared__ float acc[BN * ASTRIDE];  // ~17.4 KB
    int b = b0 + blockIdx.x, t = threadIdx.x;
    for (int i = t; i < BN * ASTRIDE; i += AGG_TPB) acc[i] = 0.f;
    __syncthreads();
    int S0 = bstart[b0];
    int s0 = bstart[b], s1 = bstart[b + 1];
    int f = t & 15;
    const int G = AGG_TPB / 16;  // 32 edge-groups
    int e = s0 + (t >> 4);
    for (; e + (UF - 1) * G < s1; e += UF * G) {
        int pv[UF];
        float v[UF];
#pragma unroll
        for (int u = 0; u < UF; u++) pv[u] = pairs[e + u * G];
#pragma unroll
        for (int u = 0; u < UF; u++)
            v[u] = __half2float(__ushort_as_half(msgu[(size_t)(e + u * G - S0) * 16 + f]));
#pragma unroll
        for (int u = 0; u < UF; u++) atomicAdd(&acc[(pv[u] & (BN - 1)) * ASTRIDE + f], v[u]);
    }
    for (; e < s1; e += G) {
        int pv = pairs[e];
        atomicAdd(&acc[(pv & (BN - 1)) * ASTRIDE + f],
                  __half2float(__ushort_as_half(msgu[(size_t)(e - S0) * 16 + f])));
    }
    __syncthreads();
    int nbase = b << NB_BITS;
    float bbf = b1[f], wwf = W2[f];
    for (int nl = t >> 4; nl < BN; nl += G) {
        int n = nbase + nl;
        float d = 0.f, p = 0.f;
        if (n < N) {
            d = dis[n];
            float self = __half2float(hs1h[(size_t)n * 16 + f]);
            p = fmaxf(d * (acc[nl * ASTRIDE + f] + self) + bbf, 0.f) * wwf;
        }
        p += __shfl_xor(p, 1);
        p += __shfl_xor(p, 2);
        p += __shfl_xor(p, 4);
        p += __shfl_xor(p, 8);
        if (f == 0 && n < N) hs2[n] = p * d;
    }
}

// layer-2: per-bucket LDS accumulate of hs2 (1MB, L2-resident gather)
__global__ void agg2_kernel(const int* __restrict__ pairs, const int* __restrict__ bstart,
                            const float* __restrict__ hs2, const float* __restrict__ dis,
                            const float* __restrict__ b2, float* __restrict__ out, int N) {
    __shared__ float acc[BN];
    int b = blockIdx.x, t = threadIdx.x;
    for (int i = t; i < BN; i += AGG_TPB) acc[i] = 0.f;
    __syncthreads();
    int s0 = bstart[b], s1 = bstart[b + 1];
    int e = s0 + t;
    for (; e + (UF - 1) * AGG_TPB < s1; e += UF * AGG_TPB) {
        int pv[UF];
        float v[UF];
#pragma unroll
        for (int u = 0; u < UF; u++) pv[u] = pairs[e + u * AGG_TPB];
#pragma unroll
        for (int u = 0; u < UF; u++) v[u] = hs2[pv[u] >> NB_BITS];
#pragma unroll
        for (int u = 0; u < UF; u++) atomicAdd(&acc[pv[u] & (BN - 1)], v[u]);
    }
    for (; e < s1; e += AGG_TPB) {
        int pv = pairs[e];
        atomicAdd(&acc[pv & (BN - 1)], hs2[pv >> NB_BITS]);
    }
    __syncthreads();
    int nbase = b << NB_BITS;
    for (int i = t; i < BN; i += AGG_TPB) {
        int n = nbase + i;
        if (n < N) out[n] = dis[n] * (acc[i] + hs2[n]) + b2[0];
    }
}

extern "C" void kernel_launch(void* const* d_in, const int* in_sizes, int n_in,
                              void* d_out, int out_size, void* d_ws, size_t ws_size,
                              hipStream_t stream) {
    const float* x = (const float*)d_in[0];
    const int* edge_index = (const int*)d_in[1];
    const float* W1 = (const float*)d_in[2];
    const float* b1 = (const float*)d_in[3];
    const float* W2 = (const float*)d_in[4];
    const float* b2 = (const float*)d_in[5];
    float* out = (float*)d_out;

    const int N = in_sizes[0] / 18;
    const int E = in_sizes[1] / 2;
    const int* src = edge_index;
    const int* dst = edge_index + E;
    const int NBUCKET = (N + BN - 1) / BN;  // 977

    // ws layout (4B words): pairs[E], srecs[E], hs1h(16N halves = 8N words),
    // hs2[N], dis[N], bstart[NBINS+1], sstart[NBINS+1], dcursor[NBINS],
    // scursor[NBINS], bcnt_d[NBINS], bcnt_s[NBINS], then msg buffer (rest).
    int* ws = (int*)d_ws;
    int* pairs = ws;
    int* srecs = pairs + (size_t)E;
    __half* hs1h = (__half*)(srecs + (size_t)E);
    float* hs2 = (float*)((int*)(srecs + (size_t)E) + 8 * (size_t)N);
    float* dis = hs2 + N;
    int* bstart = (int*)(dis + N);
    int* sstart = bstart + NBINS + 1;
    int* dcursor = sstart + NBINS + 1;
    int* scursor = dcursor + NBINS;
    int* bcnt_d = scursor + NBINS;
    int* bcnt_s = bcnt_d + NBINS;
    ushort* msgu = (ushort*)(bcnt_s + NBINS);

    // chunk the msg buffer (32B/edge) over dst-buckets to fit ws_size
    size_t fixedBytes = (size_t)((char*)msgu - (char*)d_ws);
    size_t avail = (ws_size > fixedBytes) ? (ws_size - fixedBytes) : 0;
    long capEdges = (long)(avail / 32);
    int bpc = (int)(capEdges / 4800);  // max bucket ~4094+5sigma, margin to 4800
    if (bpc < 1) bpc = 1;
    if (bpc > NBUCKET) bpc = NBUCKET;

    hipMemsetAsync(bcnt_d, 0, 2 * NBINS * sizeof(int), stream);

    int binBlocks = (E + BIN_CHUNK - 1) / BIN_CHUNK;  // 489

    bhist_kernel<<<binBlocks, BIN_TPB, 0, stream>>>(src, dst, bcnt_d, bcnt_s, E);
    bscan_kernel<<<1, NBINS, 0, stream>>>(bcnt_d, bstart, dcursor);
    bscan_kernel<<<1, NBINS, 0, stream>>>(bcnt_s, sstart, scursor);
    bplace_kernel<<<binBlocks, BIN_TPB, 0, stream>>>(src, dst, dcursor, scursor,
                                                     pairs, srecs, E);
    degdis_kernel<<<NBUCKET, 512, 0, stream>>>(pairs, bstart, dis, N);

    for (int b0 = 0; b0 < NBUCKET; b0 += bpc) {
        int b1e = min(b0 + bpc, NBUCKET);
        h1msg_kernel<<<NBUCKET, AGG_TPB, 0, stream>>>(x, W1, dis, srecs, sstart, bstart,
                                                      hs1h, msgu, b0, b1e,
                                                      (b0 == 0) ? 1 : 0, N);
        agg1_kernel<<<b1e - b0, AGG_TPB, 0, stream>>>(pairs, bstart, msgu, hs1h, dis,
                                                      b1, W2, hs2, b0, N);
    }

    agg2_kernel<<<NBUCKET, AGG_TPB, 0, stream>>>(pairs, bstart, hs2, dis, b2, out, N);
}

// Round 10
// 276.845 us; speedup vs baseline: 2.5576x; 2.5576x over previous
//
#include <hip/hip_runtime.h>
#include <hip/hip_fp16.h>

// GCN 2-layer. N=250000, E=4000000, 18 -> 16 -> 1.
// R9: CSR + register accumulation. R4/R5/R7/R8 isolated the agg1 wall: dur
// pinned at ~350us (11.4G edges/s) across random-fp32, random-fp16, and
// FULLY SEQUENTIAL reads (R8: 79MB @ 237GB/s, VALU 4.4%) -- the wall is the
// shared loop structure, not memory: 64M fp32 LDS atomicAdds (suspect: CAS
// lowering; int-atomic kernels are fast) + 16-lane broadcast pattern.
// So: sort edges by dst within bucket (per-bucket count/scan/place -> CSR
// runs), then agg1 = one node per 16-lane group, run accumulated in
// REGISTERS (no LDS, no atomics), coalesced 32B fp16 gathers, shfl epilogue.
// agg2 same treatment. h1/binning unchanged from R7 (which passed).
//
// out[d] = dis[d] * (sum_{s->d} hs[s] + hs[d]) + bias, hs pre-scaled by dis.

#define NB_BITS 8
#define BN (1 << NB_BITS)       // 256 nodes per bucket
#define NBINS 1024              // >= 977 buckets
#define BIN_TPB 512
#define BIN_CHUNK 8192
#define AGG_TPB 512
#define UF 8

// per-block LDS histogram of dst buckets -> global bcnt
__global__ void bhist_kernel(const int* __restrict__ dst, int* __restrict__ bcnt, int E) {
    __shared__ int cnt[NBINS];
    int t = threadIdx.x;
    for (int i = t; i < NBINS; i += BIN_TPB) cnt[i] = 0;
    __syncthreads();
    int base = blockIdx.x * BIN_CHUNK;
    int end = min(base + BIN_CHUNK, E);
#pragma unroll 4
    for (int e = base + t; e < end; e += BIN_TPB)
        atomicAdd(&cnt[dst[e] >> NB_BITS], 1);
    __syncthreads();
    for (int i = t; i < NBINS; i += BIN_TPB)
        if (cnt[i] > 0) atomicAdd(&bcnt[i], cnt[i]);
}

// exclusive scan of bcnt[NBINS] -> bstart, cursor
__global__ void bscan_kernel(const int* __restrict__ bcnt, int* __restrict__ bstart,
                             int* __restrict__ cursor) {
    __shared__ int s[NBINS];
    int t = threadIdx.x;  // NBINS threads
    int v = bcnt[t];
    s[t] = v;
    __syncthreads();
    for (int off = 1; off < NBINS; off <<= 1) {
        int add = (t >= off) ? s[t - off] : 0;
        __syncthreads();
        s[t] += add;
        __syncthreads();
    }
    int excl = s[t] - v;
    bstart[t] = excl;
    cursor[t] = excl;
    if (t == NBINS - 1) bstart[NBINS] = s[t];
}

// place edges: block reserves private contiguous range per bucket, writes
// packed (src<<8 | dst&255) via LDS cursors.
__global__ void bplace_kernel(const int* __restrict__ src, const int* __restrict__ dst,
                              int* __restrict__ cursor, int* __restrict__ pairs, int E) {
    __shared__ int cnt[NBINS];  // reused as local offsets after reserve
    int t = threadIdx.x;
    for (int i = t; i < NBINS; i += BIN_TPB) cnt[i] = 0;
    __syncthreads();
    int base = blockIdx.x * BIN_CHUNK;
    int end = min(base + BIN_CHUNK, E);
#pragma unroll 4
    for (int e = base + t; e < end; e += BIN_TPB)
        atomicAdd(&cnt[dst[e] >> NB_BITS], 1);
    __syncthreads();
    for (int i = t; i < NBINS; i += BIN_TPB) {
        int c = cnt[i];
        cnt[i] = (c > 0) ? atomicAdd(&cursor[i], c) : 0;
    }
    __syncthreads();
#pragma unroll 4
    for (int e = base + t; e < end; e += BIN_TPB) {
        int d = dst[e];
        int sv = src[e];
        int b = d >> NB_BITS;
        int p = atomicAdd(&cnt[b], 1);
        pairs[p] = (sv << NB_BITS) | (d & (BN - 1));   // sv < 2^18, fits
    }
}

// per-bucket CSR build: count per dst (int LDS atomics), scan, place srcs in
// dst-sorted order. Also emits dis = rsqrt(deg+1) and rowp.
__global__ void csr_kernel(const int* __restrict__ pairs, const int* __restrict__ bstart,
                           int* __restrict__ rowp, int* __restrict__ csr_src,
                           float* __restrict__ dis, int N) {
    __shared__ int cnt[BN];
    __shared__ int tmp[BN];
    int b = blockIdx.x, t = threadIdx.x;
    int s0 = bstart[b], s1 = bstart[b + 1];
    for (int i = t; i < BN; i += blockDim.x) cnt[i] = 0;
    __syncthreads();
#pragma unroll 4
    for (int e = s0 + t; e < s1; e += blockDim.x)
        atomicAdd(&cnt[pairs[e] & (BN - 1)], 1);
    __syncthreads();
    int v = (t < BN) ? cnt[t] : 0;
    if (t < BN) tmp[t] = v;
    __syncthreads();
    for (int off = 1; off < BN; off <<= 1) {
        int add = (t < BN && t >= off) ? tmp[t - off] : 0;
        __syncthreads();
        if (t < BN) tmp[t] += add;
        __syncthreads();
    }
    int nbase = b << NB_BITS;
    if (t < BN) {
        int start = s0 + tmp[t] - v;   // exclusive within bucket, global offset
        rowp[nbase + t] = start;
        int n = nbase + t;
        if (n < N) dis[n] = rsqrtf((float)v + 1.0f);
        cnt[t] = start;                // reuse as placement cursor
    }
    if (t == 0) rowp[nbase + BN] = s1; // dup of next bucket's first (same value)
    __syncthreads();
#pragma unroll 4
    for (int e = s0 + t; e < s1; e += blockDim.x) {
        int pv = pairs[e];
        int pos = atomicAdd(&cnt[pv & (BN - 1)], 1);
        csr_src[pos] = pv >> NB_BITS;
    }
}

// hs1h[n,f] = fp16( (x[n] @ W1)[f] * dis[n] )   -- 32B/row
__global__ void h1_kernel(const float* __restrict__ x, const float* __restrict__ W1,
                          const float* __restrict__ dis, __half* __restrict__ hs1h, int N) {
    __shared__ float w[18 * 16];
    for (int i = threadIdx.x; i < 18 * 16; i += blockDim.x) w[i] = W1[i];
    __syncthreads();
    int n = blockIdx.x * blockDim.x + threadIdx.x;
    if (n >= N) return;
    const float2* x2 = (const float2*)(x + (size_t)n * 18);
    float xv[18];
#pragma unroll
    for (int k = 0; k < 9; k++) {
        float2 v = x2[k];
        xv[2 * k] = v.x;
        xv[2 * k + 1] = v.y;
    }
    float d = dis[n];
    float acc[16];
#pragma unroll
    for (int f = 0; f < 16; f++) acc[f] = 0.0f;
#pragma unroll
    for (int k = 0; k < 18; k++) {
        float xk = xv[k];
#pragma unroll
        for (int f = 0; f < 16; f++) acc[f] = fmaf(xk, w[k * 16 + f], acc[f]);
    }
    unsigned int u[8];
#pragma unroll
    for (int q = 0; q < 8; q++) {
        unsigned int lo = __half_as_ushort(__float2half_rn(acc[2 * q] * d));
        unsigned int hi = __half_as_ushort(__float2half_rn(acc[2 * q + 1] * d));
        u[q] = lo | (hi << 16);
    }
    uint4* outp = (uint4*)(hs1h + (size_t)n * 16);
    outp[0] = make_uint4(u[0], u[1], u[2], u[3]);
    outp[1] = make_uint4(u[4], u[5], u[6], u[7]);
}

// layer-1: CSR, one node per 16-lane group, REGISTER accumulation.
// No LDS, no atomics. Gathers are 32B coalesced per edge.
// epilogue: relu + W2 dot + dis scale -> hs2 (fp32)
__global__ void agg1_kernel(const int* __restrict__ csr_src, const int* __restrict__ rowp,
                            const __half* __restrict__ hs1h, const float* __restrict__ dis,
                            const float* __restrict__ b1, const float* __restrict__ W2,
                            float* __restrict__ hs2, int N) {
    int b = blockIdx.x, t = threadIdx.x;
    int f = t & 15;
    int g = t >> 4;                 // 0..31 groups
    float bbf = b1[f], wwf = W2[f];
    int nbase = b << NB_BITS;
    for (int nl = g; nl < BN; nl += AGG_TPB / 16) {
        int n = nbase + nl;
        if (n >= N) continue;
        int r0 = rowp[n], r1 = rowp[n + 1];
        float a = 0.f;
#pragma unroll 4
        for (int r = r0; r < r1; ++r) {
            int s = csr_src[r];     // group-uniform broadcast load
            a += __half2float(hs1h[(size_t)s * 16 + f]);
        }
        float d = dis[n];
        float self = __half2float(hs1h[(size_t)n * 16 + f]);
        float p = fmaxf(d * (a + self) + bbf, 0.f) * wwf;
        p += __shfl_xor(p, 1);
        p += __shfl_xor(p, 2);
        p += __shfl_xor(p, 4);
        p += __shfl_xor(p, 8);
        if (f == 0) hs2[n] = p * d;
    }
}

// layer-2: CSR, one node per 16-lane group; lanes split the run, shfl reduce.
// hs2 is 1MB -> L2-resident gather.
__global__ void agg2_kernel(const int* __restrict__ csr_src, const int* __restrict__ rowp,
                            const float* __restrict__ hs2, const float* __restrict__ dis,
                            const float* __restrict__ b2, float* __restrict__ out, int N) {
    int b = blockIdx.x, t = threadIdx.x;
    int l = t & 15;
    int g = t >> 4;
    int nbase = b << NB_BITS;
    float bb = b2[0];
    for (int nl = g; nl < BN; nl += AGG_TPB / 16) {
        int n = nbase + nl;
        if (n >= N) continue;
        int r0 = rowp[n], r1 = rowp[n + 1];
        float a = 0.f;
        for (int r = r0 + l; r < r1; r += 16) a += hs2[csr_src[r]];
        a += __shfl_xor(a, 1);
        a += __shfl_xor(a, 2);
        a += __shfl_xor(a, 4);
        a += __shfl_xor(a, 8);
        if (l == 0) out[n] = dis[n] * (a + hs2[n]) + bb;
    }
}

extern "C" void kernel_launch(void* const* d_in, const int* in_sizes, int n_in,
                              void* d_out, int out_size, void* d_ws, size_t ws_size,
                              hipStream_t stream) {
    const float* x = (const float*)d_in[0];
    const int* edge_index = (const int*)d_in[1];
    const float* W1 = (const float*)d_in[2];
    const float* b1 = (const float*)d_in[3];
    const float* W2 = (const float*)d_in[4];
    const float* b2 = (const float*)d_in[5];
    float* out = (float*)d_out;

    const int N = in_sizes[0] / 18;
    const int E = in_sizes[1] / 2;
    const int* src = edge_index;
    const int* dst = edge_index + E;
    const int NBUCKET = (N + BN - 1) / BN;  // 977

    // ws layout (4B words): pairs[E], csr_src[E], hs1h(16N halves = 8N words),
    // hs2[N], dis[N], rowp[NBUCKET*BN+1], bstart[NBINS+1], cursor[NBINS],
    // bcnt[NBINS]  ~= 43 MB
    int* ws = (int*)d_ws;
    int* pairs = ws;
    int* csr_src = pairs + (size_t)E;
    __half* hs1h = (__half*)(csr_src + (size_t)E);
    float* hs2 = (float*)((int*)(csr_src + (size_t)E) + 8 * (size_t)N);
    float* dis = hs2 + N;
    int* rowp = (int*)(dis + N);
    int* bstart = rowp + (size_t)NBUCKET * BN + 1;
    int* cursor = bstart + NBINS + 1;
    int* bcnt = cursor + NBINS;

    hipMemsetAsync(bcnt, 0, NBINS * sizeof(int), stream);

    int binBlocks = (E + BIN_CHUNK - 1) / BIN_CHUNK;  // 489
    int nBlocksN = (N + 255) / 256;

    bhist_kernel<<<binBlocks, BIN_TPB, 0, stream>>>(dst, bcnt, E);
    bscan_kernel<<<1, NBINS, 0, stream>>>(bcnt, bstart, cursor);
    bplace_kernel<<<binBlocks, BIN_TPB, 0, stream>>>(src, dst, cursor, pairs, E);
    csr_kernel<<<NBUCKET, 512, 0, stream>>>(pairs, bstart, rowp, csr_src, dis, N);
    h1_kernel<<<nBlocksN, 256, 0, stream>>>(x, W1, dis, hs1h, N);
    agg1_kernel<<<NBUCKET, AGG_TPB, 0, stream>>>(csr_src, rowp, hs1h, dis, b1, W2, hs2, N);
    agg2_kernel<<<NBUCKET, AGG_TPB, 0, stream>>>(csr_src, rowp, hs2, dis, b2, out, N);
}

// Round 11
// 254.070 us; speedup vs baseline: 2.7868x; 1.0896x over previous
//
#include <hip/hip_runtime.h>
#include <hip/hip_fp16.h>

// GCN 2-layer. N=250000, E=4000000, 18 -> 16 -> 1.
// R11: coalesced bplace. R10 (CSR + register agg) landed 277us and exposed
// bplace as #1 (88us): scattered 4B stores into 16MB -> WRITE_SIZE 100MB
// (6x line amplification) at 1.4TB/s drain. Fix: block-local counting sort
// (LDS hist[512] -> scan -> LDS scatter of 8192 edges) then copy out in
// bin-sorted order -> per-bin runs of ~17 edges land contiguously
// (amplification ~1.9x). Sort bins = 512 dst nodes (489 bins, one per
// thread). csr adapts to 512-node bins; h1/agg1/agg2 frozen from R10.
//
// out[d] = dis[d] * (sum_{s->d} hs[s] + hs[d]) + bias, hs pre-scaled by dis.

#define NB_BITS 8
#define BN (1 << NB_BITS)       // 256 nodes per agg bucket (agg1 grid)
#define SB_BITS 9
#define SBN (1 << SB_BITS)      // 512 nodes per sort bin
#define NSB 512                 // padded bin count (489 used)
#define BIN_TPB 512
#define BIN_CHUNK 8192
#define AGG_TPB 512

// per-block LDS histogram of dst sort-bins -> global bcnt
__global__ void bhist_kernel(const int* __restrict__ dst, int* __restrict__ bcnt, int E) {
    __shared__ int cnt[NSB];
    int t = threadIdx.x;        // BIN_TPB == NSB == 512
    cnt[t] = 0;
    __syncthreads();
    int base = blockIdx.x * BIN_CHUNK;
    int end = min(base + BIN_CHUNK, E);
#pragma unroll 4
    for (int e = base + t; e < end; e += BIN_TPB)
        atomicAdd(&cnt[dst[e] >> SB_BITS], 1);
    __syncthreads();
    if (cnt[t] > 0) atomicAdd(&bcnt[t], cnt[t]);
}

// exclusive scan of bcnt[NSB] -> bstart, cursor
__global__ void bscan_kernel(const int* __restrict__ bcnt, int* __restrict__ bstart,
                             int* __restrict__ cursor) {
    __shared__ int s[NSB];
    int t = threadIdx.x;  // NSB threads
    int v = bcnt[t];
    s[t] = v;
    __syncthreads();
    for (int off = 1; off < NSB; off <<= 1) {
        int add = (t >= off) ? s[t - off] : 0;
        __syncthreads();
        s[t] += add;
        __syncthreads();
    }
    int excl = s[t] - v;
    bstart[t] = excl;
    cursor[t] = excl;
    if (t == NSB - 1) bstart[NSB] = s[t];
}

// place edges with block-local counting sort -> coalesced run writes.
// pairs value = (src<<9 | dst&511), bin-contiguous in global memory.
__global__ void bplace_kernel(const int* __restrict__ src, const int* __restrict__ dst,
                              int* __restrict__ cursor, int* __restrict__ pairs, int E) {
    __shared__ int cnt[NSB];
    __shared__ int lstart[NSB];
    __shared__ int lcur[NSB];
    __shared__ int gbase[NSB];
    __shared__ int lbuf[BIN_CHUNK];            // 32KB
    __shared__ unsigned short lbin[BIN_CHUNK]; // 16KB
    int t = threadIdx.x;
    int base = blockIdx.x * BIN_CHUNK;
    int end = min(base + BIN_CHUNK, E);
    cnt[t] = 0;
    __syncthreads();
#pragma unroll 4
    for (int e = base + t; e < end; e += BIN_TPB)
        atomicAdd(&cnt[dst[e] >> SB_BITS], 1);
    __syncthreads();
    // inclusive scan of cnt (Hillis-Steele in lstart)
    int v = cnt[t];
    lstart[t] = v;
    __syncthreads();
    for (int off = 1; off < NSB; off <<= 1) {
        int add = (t >= off) ? lstart[t - off] : 0;
        __syncthreads();
        lstart[t] += add;
        __syncthreads();
    }
    int excl = lstart[t] - v;   // own-index reads only below: no hazard
    lstart[t] = excl;
    lcur[t] = excl;
    gbase[t] = (v > 0) ? atomicAdd(&cursor[t], v) : 0;
    __syncthreads();
    // scatter into LDS in bin-sorted order
#pragma unroll 2
    for (int e = base + t; e < end; e += BIN_TPB) {
        int d = dst[e], s = src[e];
        int b = d >> SB_BITS;
        int pos = atomicAdd(&lcur[b], 1);
        lbuf[pos] = (s << SB_BITS) | (d & (SBN - 1));
        lbin[pos] = (unsigned short)b;
    }
    __syncthreads();
    // copy out: consecutive i within a bin -> consecutive global addresses
    int n = end - base;
#pragma unroll 4
    for (int i = t; i < n; i += BIN_TPB) {
        int b = lbin[i];
        pairs[gbase[b] + (i - lstart[b])] = lbuf[i];
    }
}

// per-bin CSR build: count per dst (int LDS atomics), scan, place srcs in
// dst-sorted order. Emits rowp, csr_src, dis = rsqrt(deg+1).
__global__ void csr_kernel(const int* __restrict__ pairs, const int* __restrict__ bstart,
                           int* __restrict__ rowp, int* __restrict__ csr_src,
                           float* __restrict__ dis, int N) {
    __shared__ int cnt[SBN];
    __shared__ int tmp[SBN];
    int b = blockIdx.x, t = threadIdx.x;   // TPB == SBN == 512
    int s0 = bstart[b], s1 = bstart[b + 1];
    cnt[t] = 0;
    __syncthreads();
#pragma unroll 4
    for (int e = s0 + t; e < s1; e += SBN)
        atomicAdd(&cnt[pairs[e] & (SBN - 1)], 1);
    __syncthreads();
    int v = cnt[t];
    tmp[t] = v;
    __syncthreads();
    for (int off = 1; off < SBN; off <<= 1) {
        int add = (t >= off) ? tmp[t - off] : 0;
        __syncthreads();
        tmp[t] += add;
        __syncthreads();
    }
    int nbase = b << SB_BITS;
    int start = s0 + tmp[t] - v;   // exclusive within bin, global offset
    rowp[nbase + t] = start;
    int n = nbase + t;
    if (n < N) dis[n] = rsqrtf((float)v + 1.0f);
    cnt[t] = start;                // reuse as placement cursor
    if (t == 0) rowp[nbase + SBN] = s1;  // boundary (dup of next bin's first)
    __syncthreads();
#pragma unroll 4
    for (int e = s0 + t; e < s1; e += SBN) {
        int pv = pairs[e];
        int pos = atomicAdd(&cnt[pv & (SBN - 1)], 1);
        csr_src[pos] = pv >> SB_BITS;
    }
}

// hs1h[n,f] = fp16( (x[n] @ W1)[f] * dis[n] )   -- 32B/row
__global__ void h1_kernel(const float* __restrict__ x, const float* __restrict__ W1,
                          const float* __restrict__ dis, __half* __restrict__ hs1h, int N) {
    __shared__ float w[18 * 16];
    for (int i = threadIdx.x; i < 18 * 16; i += blockDim.x) w[i] = W1[i];
    __syncthreads();
    int n = blockIdx.x * blockDim.x + threadIdx.x;
    if (n >= N) return;
    const float2* x2 = (const float2*)(x + (size_t)n * 18);
    float xv[18];
#pragma unroll
    for (int k = 0; k < 9; k++) {
        float2 v = x2[k];
        xv[2 * k] = v.x;
        xv[2 * k + 1] = v.y;
    }
    float d = dis[n];
    float acc[16];
#pragma unroll
    for (int f = 0; f < 16; f++) acc[f] = 0.0f;
#pragma unroll
    for (int k = 0; k < 18; k++) {
        float xk = xv[k];
#pragma unroll
        for (int f = 0; f < 16; f++) acc[f] = fmaf(xk, w[k * 16 + f], acc[f]);
    }
    unsigned int u[8];
#pragma unroll
    for (int q = 0; q < 8; q++) {
        unsigned int lo = __half_as_ushort(__float2half_rn(acc[2 * q] * d));
        unsigned int hi = __half_as_ushort(__float2half_rn(acc[2 * q + 1] * d));
        u[q] = lo | (hi << 16);
    }
    uint4* outp = (uint4*)(hs1h + (size_t)n * 16);
    outp[0] = make_uint4(u[0], u[1], u[2], u[3]);
    outp[1] = make_uint4(u[4], u[5], u[6], u[7]);
}

// layer-1: CSR, one node per 16-lane group, REGISTER accumulation.
// No LDS, no atomics. epilogue: relu + W2 dot + dis scale -> hs2
__global__ void agg1_kernel(const int* __restrict__ csr_src, const int* __restrict__ rowp,
                            const __half* __restrict__ hs1h, const float* __restrict__ dis,
                            const float* __restrict__ b1, const float* __restrict__ W2,
                            float* __restrict__ hs2, int N) {
    int b = blockIdx.x, t = threadIdx.x;
    int f = t & 15;
    int g = t >> 4;                 // 0..31 groups
    float bbf = b1[f], wwf = W2[f];
    int nbase = b << NB_BITS;
    for (int nl = g; nl < BN; nl += AGG_TPB / 16) {
        int n = nbase + nl;
        if (n >= N) continue;
        int r0 = rowp[n], r1 = rowp[n + 1];
        float a = 0.f;
#pragma unroll 4
        for (int r = r0; r < r1; ++r) {
            int s = csr_src[r];     // group-uniform broadcast load
            a += __half2float(hs1h[(size_t)s * 16 + f]);
        }
        float d = dis[n];
        float self = __half2float(hs1h[(size_t)n * 16 + f]);
        float p = fmaxf(d * (a + self) + bbf, 0.f) * wwf;
        p += __shfl_xor(p, 1);
        p += __shfl_xor(p, 2);
        p += __shfl_xor(p, 4);
        p += __shfl_xor(p, 8);
        if (f == 0) hs2[n] = p * d;
    }
}

// layer-2: CSR, one node per 16-lane group; lanes split the run, shfl reduce.
__global__ void agg2_kernel(const int* __restrict__ csr_src, const int* __restrict__ rowp,
                            const float* __restrict__ hs2, const float* __restrict__ dis,
                            const float* __restrict__ b2, float* __restrict__ out, int N) {
    int b = blockIdx.x, t = threadIdx.x;
    int l = t & 15;
    int g = t >> 4;
    int nbase = b << NB_BITS;
    float bb = b2[0];
    for (int nl = g; nl < BN; nl += AGG_TPB / 16) {
        int n = nbase + nl;
        if (n >= N) continue;
        int r0 = rowp[n], r1 = rowp[n + 1];
        float a = 0.f;
        for (int r = r0 + l; r < r1; r += 16) a += hs2[csr_src[r]];
        a += __shfl_xor(a, 1);
        a += __shfl_xor(a, 2);
        a += __shfl_xor(a, 4);
        a += __shfl_xor(a, 8);
        if (l == 0) out[n] = dis[n] * (a + hs2[n]) + bb;
    }
}

extern "C" void kernel_launch(void* const* d_in, const int* in_sizes, int n_in,
                              void* d_out, int out_size, void* d_ws, size_t ws_size,
                              hipStream_t stream) {
    const float* x = (const float*)d_in[0];
    const int* edge_index = (const int*)d_in[1];
    const float* W1 = (const float*)d_in[2];
    const float* b1 = (const float*)d_in[3];
    const float* W2 = (const float*)d_in[4];
    const float* b2 = (const float*)d_in[5];
    float* out = (float*)d_out;

    const int N = in_sizes[0] / 18;
    const int E = in_sizes[1] / 2;
    const int* src = edge_index;
    const int* dst = edge_index + E;
    const int NABUCKET = (N + BN - 1) / BN;    // 977 agg blocks
    const int NSBUCKET = (N + SBN - 1) / SBN;  // 489 sort bins

    // ws layout (4B words): pairs[E], csr_src[E], hs1h(16N halves = 8N words),
    // hs2[N], dis[N], rowp[NSBUCKET*SBN+1], bstart[NSB+1], cursor[NSB],
    // bcnt[NSB]  ~= 43 MB
    int* ws = (int*)d_ws;
    int* pairs = ws;
    int* csr_src = pairs + (size_t)E;
    __half* hs1h = (__half*)(csr_src + (size_t)E);
    float* hs2 = (float*)((int*)(csr_src + (size_t)E) + 8 * (size_t)N);
    float* dis = hs2 + N;
    int* rowp = (int*)(dis + N);
    int* bstart = rowp + (size_t)NSBUCKET * SBN + 1;
    int* cursor = bstart + NSB + 1;
    int* bcnt = cursor + NSB;

    hipMemsetAsync(bcnt, 0, NSB * sizeof(int), stream);

    int binBlocks = (E + BIN_CHUNK - 1) / BIN_CHUNK;  // 489
    int nBlocksN = (N + 255) / 256;

    bhist_kernel<<<binBlocks, BIN_TPB, 0, stream>>>(dst, bcnt, E);
    bscan_kernel<<<1, NSB, 0, stream>>>(bcnt, bstart, cursor);
    bplace_kernel<<<binBlocks, BIN_TPB, 0, stream>>>(src, dst, cursor, pairs, E);
    csr_kernel<<<NSBUCKET, SBN, 0, stream>>>(pairs, bstart, rowp, csr_src, dis, N);
    h1_kernel<<<nBlocksN, 256, 0, stream>>>(x, W1, dis, hs1h, N);
    agg1_kernel<<<NABUCKET, AGG_TPB, 0, stream>>>(csr_src, rowp, hs1h, dis, b1, W2, hs2, N);
    agg2_kernel<<<NABUCKET, AGG_TPB, 0, stream>>>(csr_src, rowp, hs2, dis, b2, out, N);
}